// Round 3
// baseline (459.425 us; speedup 1.0000x reference)
//
#include <hip/hip_runtime.h>

// ---------------------------------------------------------------------------
// Block = x + attn(ln1(x)); x = x + attn(ln2(x))   (attn twice, no MLP,
// no causal mask, softmax scale = C^-0.5).  B=4 T=2048 C=768 H=12 hd=64.
// R13 = R12 (386us, attn 71us) with attn staging/geometry reworked:
//  - LDS rows padded to 68 ushorts (136B) = R10's proven 0-conflict stride;
//    staged via reg (global->reg early, ds_write late, T14) since
//    global_load_lds cannot produce padded rows (its conflict was 4/read).
//  - 2-wave blocks, 64 q rows per wave: K/V fragments read once per wave,
//    reused across two 32x32 q-subtiles -> DS reads per unit work halved.
//  - keeps R12's 32x32x16 MFMA + in-register P via permlane32_swap + VALU l.
//  - setprio(1) around MFMA clusters (m191: +4-7% attn).
// ---------------------------------------------------------------------------

using bf16x8 = __attribute__((ext_vector_type(8))) short;   // 8 bf16 = 4 VGPRs
using f32x4  = __attribute__((ext_vector_type(4))) float;
using f32x16 = __attribute__((ext_vector_type(16))) float;

__device__ __forceinline__ unsigned short f2b(float f) {
  unsigned u = __builtin_bit_cast(unsigned, f);
  u += 0x7FFFu + ((u >> 16) & 1u);          // RNE
  return (unsigned short)(u >> 16);
}
// pack two floats -> two bf16 (RNE) in one dword: lo=a, hi=b
__device__ __forceinline__ unsigned pk2(float a, float b) {
  unsigned ua = __builtin_bit_cast(unsigned, a);
  ua += 0x7FFFu + ((ua >> 16) & 1u);
  unsigned ub = __builtin_bit_cast(unsigned, b);
  ub += 0x7FFFu + ((ub >> 16) & 1u);
  return (ua >> 16) | (ub & 0xFFFF0000u);
}

__device__ __forceinline__ bf16x8 mk8(unsigned a, unsigned b, unsigned c,
                                      unsigned d) {
  union { unsigned u[4]; bf16x8 v; } x;
  x.u[0] = a; x.u[1] = b; x.u[2] = c; x.u[3] = d;
  return x.v;
}

#define ASYNC16(g, l)                                                        \
  __builtin_amdgcn_global_load_lds(                                          \
      (const __attribute__((address_space(1))) void*)(g),                    \
      (__attribute__((address_space(3))) void*)(l), 16, 0, 0)

// swap a.hi32lanes <-> b.lo32lanes (V_PERMLANE32_SWAP_B32)
#define PLSWAP(a, b) asm("v_permlane32_swap_b32 %0, %1" : "+v"(a), "+v"(b))

// ---------------------------------------------------------------------------
// Weight transpose+cast: w (768, N) fp32  ->  wt (N, 768) bf16
// ---------------------------------------------------------------------------
__global__ __launch_bounds__(256) void wt_kernel(const float* __restrict__ w,
                                                 unsigned short* __restrict__ wt,
                                                 int N) {
  __shared__ float tile[32][33];
  const int n0 = blockIdx.x * 32, k0 = blockIdx.y * 32;
  const int tx = threadIdx.x, ty = threadIdx.y;  // (32, 8)
#pragma unroll
  for (int i = 0; i < 32; i += 8)
    tile[ty + i][tx] = w[(size_t)(k0 + ty + i) * N + n0 + tx];
  __syncthreads();
#pragma unroll
  for (int i = 0; i < 32; i += 8)
    wt[(size_t)(n0 + ty + i) * 768 + k0 + tx] = f2b(tile[tx][ty + i]);
}

// ---------------------------------------------------------------------------
// LayerNorm: x (8192, 768) fp32 -> h bf16.  One block per row.
// ---------------------------------------------------------------------------
__global__ __launch_bounds__(256) void ln_kernel(const float* __restrict__ x,
                                                 const float* __restrict__ g,
                                                 const float* __restrict__ b,
                                                 unsigned short* __restrict__ h) {
  __shared__ float red[8];
  const int row = blockIdx.x;
  const int tid = threadIdx.x;
  const float* xr = x + (size_t)row * 768;
  float v0 = xr[tid], v1 = xr[tid + 256], v2 = xr[tid + 512];
  float s = v0 + v1 + v2;
  float s2 = v0 * v0 + v1 * v1 + v2 * v2;
#pragma unroll
  for (int off = 1; off < 64; off <<= 1) {
    s += __shfl_xor(s, off);
    s2 += __shfl_xor(s2, off);
  }
  if ((tid & 63) == 0) { red[tid >> 6] = s; red[4 + (tid >> 6)] = s2; }
  __syncthreads();
  const float S  = red[0] + red[1] + red[2] + red[3];
  const float S2 = red[4] + red[5] + red[6] + red[7];
  const float mu  = S * (1.0f / 768.0f);
  const float var = S2 * (1.0f / 768.0f) - mu * mu;
  const float inv = rsqrtf(var + 1e-5f);
  unsigned short* hr = h + (size_t)row * 768;
  hr[tid]       = f2b((v0 - mu) * inv * g[tid] + b[tid]);
  hr[tid + 256] = f2b((v1 - mu) * inv * g[tid + 256] + b[tid + 256]);
  hr[tid + 512] = f2b((v2 - mu) * inv * g[tid + 512] + b[tid + 512]);
}

// ---------------------------------------------------------------------------
// bf16 GEMM, m97 pattern: A (M,768) bf16 row-major, Bt (N,768) bf16,
// 128x128 tile, BK=32, 4 waves x 4x4 mfma tiles.
// EPI 0: scatter qkv (+bias): q (scaled by c2), k -> (bh,t,d) b16 stores;
//        v -> V^T (bh,d,t) with PACKED b64 stores (r values are t-contig).
// EPI 1: out fp32 = resid + bias + acc.
// ---------------------------------------------------------------------------
template <int EPI>
__global__ __launch_bounds__(256, 2) void gemm_kernel(
    const unsigned short* __restrict__ A, const unsigned short* __restrict__ Bt,
    const float* __restrict__ bias, const float* __restrict__ resid,
    unsigned short* __restrict__ q, unsigned short* __restrict__ k,
    unsigned short* __restrict__ vt, float* __restrict__ outF) {
  __shared__ alignas(16) unsigned short As[128 * 32];
  __shared__ alignas(16) unsigned short Bs[128 * 32];

  const int tid = threadIdx.x;
  const int wv = tid >> 6;
  const int lane = tid & 63;
  const int quad = lane >> 4;
  const int l15 = lane & 15;
  const int m0 = blockIdx.y * 128;
  const int n0 = blockIdx.x * 128;

  const int o0 = wv * 1024 + lane * 16;
  const int rT0 = o0 >> 6, c0 = (o0 & 63) >> 1;
  const int o1 = o0 + 4096;
  const int rT1 = o1 >> 6, c1 = (o1 & 63) >> 1;

  const unsigned short* gA0 = A + (size_t)(m0 + rT0) * 768 + c0;
  const unsigned short* gA1 = A + (size_t)(m0 + rT1) * 768 + c1;
  const unsigned short* gB0 = Bt + (size_t)(n0 + rT0) * 768 + c0;
  const unsigned short* gB1 = Bt + (size_t)(n0 + rT1) * 768 + c1;
  unsigned short* lA0 = &As[wv * 512];
  unsigned short* lA1 = &As[wv * 512 + 2048];
  unsigned short* lB0 = &Bs[wv * 512];
  unsigned short* lB1 = &Bs[wv * 512 + 2048];

  f32x4 acc[4][4];
#pragma unroll
  for (int i = 0; i < 4; ++i)
#pragma unroll
    for (int j = 0; j < 4; ++j) acc[i][j] = {0.f, 0.f, 0.f, 0.f};

  const int mBase = (wv >> 1) * 64;
  const int nBase = (wv & 1) * 64;

  for (int kk = 0; kk < 24; ++kk) {
    const int ko = kk * 32;
    ASYNC16(gA0 + ko, lA0);
    ASYNC16(gA1 + ko, lA1);
    ASYNC16(gB0 + ko, lB0);
    ASYNC16(gB1 + ko, lB1);
    __syncthreads();
    bf16x8 af[4], bfv[4];
#pragma unroll
    for (int mt = 0; mt < 4; ++mt)
      af[mt] = *(const bf16x8*)&As[(mBase + mt * 16 + l15) * 32 + quad * 8];
#pragma unroll
    for (int nt = 0; nt < 4; ++nt)
      bfv[nt] = *(const bf16x8*)&Bs[(nBase + nt * 16 + l15) * 32 + quad * 8];
#pragma unroll
    for (int mt = 0; mt < 4; ++mt)
#pragma unroll
      for (int nt = 0; nt < 4; ++nt)
        acc[mt][nt] = __builtin_amdgcn_mfma_f32_16x16x32_bf16(af[mt], bfv[nt],
                                                              acc[mt][nt], 0, 0, 0);
    __syncthreads();
  }

  if constexpr (EPI == 0) {
    const float c2 = 0.052062786090587f;  // 768^-0.5 * log2(e), folded into Q
#pragma unroll
    for (int mt = 0; mt < 4; ++mt) {
#pragma unroll
      for (int nt = 0; nt < 4; ++nt) {
        const int n = n0 + nBase + nt * 16 + l15;
        const int head = n / 192;
        const int rem = n - head * 192;
        const int sel = rem >> 6;
        const int d = rem & 63;
        const float bv = bias[n];
        const int mr = m0 + mBase + mt * 16 + quad * 4;   // r=0 row
        const int bb = mr >> 11;
        const int t = mr & 2047;
        if (sel == 2) {
          // V^T (bh,d,t): 4 r-values are t-contiguous -> one b64 store
          const unsigned long long pk =
              (unsigned long long)pk2(acc[mt][nt][0] + bv, acc[mt][nt][1] + bv) |
              ((unsigned long long)pk2(acc[mt][nt][2] + bv, acc[mt][nt][3] + bv) << 32);
          *(unsigned long long*)&vt[(((size_t)bb * 12 + head) * 64 + d) * 2048 + t] = pk;
        } else {
          unsigned short* tgt = (sel == 0) ? q : k;
          const float sc = (sel == 0) ? c2 : 1.0f;
#pragma unroll
          for (int r = 0; r < 4; ++r)
            tgt[(((size_t)bb * 12 + head) * 2048 + t + r) * 64 + d] =
                f2b((acc[mt][nt][r] + bv) * sc);
        }
      }
    }
  } else {
#pragma unroll
    for (int mt = 0; mt < 4; ++mt) {
#pragma unroll
      for (int nt = 0; nt < 4; ++nt) {
        const int n = n0 + nBase + nt * 16 + l15;
        const float bv = bias[n];
#pragma unroll
        for (int r = 0; r < 4; ++r) {
          const int m = m0 + mBase + mt * 16 + quad * 4 + r;
          const size_t idx = (size_t)m * 768 + n;
          outF[idx] = resid[idx] + bv + acc[mt][nt][r];
        }
      }
    }
  }
}

// ---------------------------------------------------------------------------
// Flash attention (R13 body): 32x32x16 MFMA, in-register P via permlane,
// reg-staged K/V into PAD-68 LDS (0-conflict stride), 2 waves x 64q.
//   S^T = K Q^T (Q pre-scaled by c2) -> P = exp2(S^T) truncated to bf16 in
//   regs -> O^T += V^T P^T ;  l += sum(P) in VALU.  Fixed-max softmax.
// Per wave: 64 q rows (two 32x32 subtiles), chunk = 64 t.  Block: 2 waves.
// ---------------------------------------------------------------------------
#define KPAD 68
__global__ __launch_bounds__(128, 2) void attn_kernel(
    const unsigned short* __restrict__ Q, const unsigned short* __restrict__ Km,
    const unsigned short* __restrict__ Vt, unsigned short* __restrict__ Y) {
  __shared__ alignas(16) unsigned short Ks[2][64 * KPAD];  // [t][d], pad 68
  __shared__ alignas(16) unsigned short Vs[2][64 * KPAD];  // [d][t], pad 68

  const int bh   = blockIdx.x;
  const int qt   = blockIdx.y;
  const int tid  = threadIdx.x;       // 0..127
  const int wv   = tid >> 6;          // 0..1
  const int lane = tid & 63;
  const int l31  = lane & 31;
  const int hi   = lane >> 5;
  const size_t bhT = (size_t)bh * 2048;

  // ---- Q fragments: B-operand, lane holds Q[q][d=ks*16+hi*8+j] ------------
  bf16x8 qf0[4], qf1[4];
  {
    const unsigned short* qa =
        Q + (bhT + qt * 128 + wv * 64 + l31) * 64 + hi * 8;
#pragma unroll
    for (int ks = 0; ks < 4; ++ks) {
      qf0[ks] = *(const bf16x8*)(qa + ks * 16);
      qf1[ks] = *(const bf16x8*)(qa + 32 * 64 + ks * 16);
    }
  }

  // ---- staging geometry: lane pair covers one 128B row --------------------
  const int sr = tid >> 1;            // 0..63 (row)
  const int sh = tid & 1;             // half-row
  const unsigned short* gK = Km + (bhT + sr) * 64 + sh * 32;
  const unsigned short* gV = Vt + ((size_t)bh * 64 + sr) * 2048 + sh * 32;
  const int lofs = sr * KPAD + sh * 32;   // ushort index into Ks/Vs rows

  f32x16 o00, o01, o10, o11;          // o[qs][dt]
#pragma unroll
  for (int i = 0; i < 16; ++i) { o00[i] = 0.f; o01[i] = 0.f; o10[i] = 0.f; o11[i] = 0.f; }
  float l0 = 0.f, l1 = 0.f;

  bf16x8 kst[4], vst[4];
  // prologue: load + write chunk 0 into buf 0
#pragma unroll
  for (int i = 0; i < 4; ++i) {
    kst[i] = *(const bf16x8*)(gK + i * 8);
    vst[i] = *(const bf16x8*)(gV + i * 8);
  }
#pragma unroll
  for (int i = 0; i < 4; ++i) {
    *(bf16x8*)&Ks[0][lofs + i * 8] = kst[i];
    *(bf16x8*)&Vs[0][lofs + i * 8] = vst[i];
  }
  __syncthreads();

  for (int c = 0; c < 32; ++c) {
    const int p = c & 1;
    if (c < 31) {  // issue next-chunk global loads; land during compute (T14)
      const unsigned short* gKn = gK + (size_t)(c + 1) * 4096;
      const unsigned short* gVn = gV + (c + 1) * 64;
#pragma unroll
      for (int i = 0; i < 4; ++i) {
        kst[i] = *(const bf16x8*)(gKn + i * 8);
        vst[i] = *(const bf16x8*)(gVn + i * 8);
      }
    }
    const unsigned short* Kp = &Ks[p][0];
    const unsigned short* Vp = &Vs[p][0];

#pragma unroll
    for (int tt = 0; tt < 2; ++tt) {
      // ---- K fragments for this t-subtile (reused by both q-subtiles) ----
      bf16x8 kf[4];
#pragma unroll
      for (int ks = 0; ks < 4; ++ks)
        kf[ks] = *(const bf16x8*)&Kp[(tt * 32 + l31) * KPAD + ks * 16 + hi * 8];

      // ---- S tiles (32t x 32q) for qs=0,1: chained k-steps ----
      f32x16 s0, s1;
#pragma unroll
      for (int i = 0; i < 16; ++i) { s0[i] = 0.f; s1[i] = 0.f; }
      __builtin_amdgcn_s_setprio(1);
#pragma unroll
      for (int ks = 0; ks < 4; ++ks) {
        s0 = __builtin_amdgcn_mfma_f32_32x32x16_bf16(kf[ks], qf0[ks], s0, 0, 0, 0);
        s1 = __builtin_amdgcn_mfma_f32_32x32x16_bf16(kf[ks], qf1[ks], s1, 0, 0, 0);
      }
      __builtin_amdgcn_s_setprio(0);

      // ---- P = exp2(S), truncate to bf16; l += truncated values ----
      unsigned dwa[8], dwb[8];
      {
        float lc0 = 0.f, lc1 = 0.f;
#pragma unroll
        for (int r2 = 0; r2 < 8; ++r2) {
          const float a0 = __builtin_amdgcn_exp2f(s0[2 * r2]);
          const float a1 = __builtin_amdgcn_exp2f(s0[2 * r2 + 1]);
          const unsigned ua0 = __builtin_bit_cast(unsigned, a0) & 0xFFFF0000u;
          const unsigned ua1 = __builtin_bit_cast(unsigned, a1) & 0xFFFF0000u;
          lc0 += __builtin_bit_cast(float, ua0) + __builtin_bit_cast(float, ua1);
          dwa[r2] = (ua0 >> 16) | ua1;
          const float b0 = __builtin_amdgcn_exp2f(s1[2 * r2]);
          const float b1 = __builtin_amdgcn_exp2f(s1[2 * r2 + 1]);
          const unsigned ub0 = __builtin_bit_cast(unsigned, b0) & 0xFFFF0000u;
          const unsigned ub1 = __builtin_bit_cast(unsigned, b1) & 0xFFFF0000u;
          lc1 += __builtin_bit_cast(float, ub0) + __builtin_bit_cast(float, ub1);
          dwb[r2] = (ub0 >> 16) | ub1;
        }
        l0 += lc0;
        l1 += lc1;
      }

      // ---- C-layout -> B-frag: one swap yields two pf words ----
      PLSWAP(dwa[0], dwa[2]); PLSWAP(dwa[1], dwa[3]);
      PLSWAP(dwa[4], dwa[6]); PLSWAP(dwa[5], dwa[7]);
      PLSWAP(dwb[0], dwb[2]); PLSWAP(dwb[1], dwb[3]);
      PLSWAP(dwb[4], dwb[6]); PLSWAP(dwb[5], dwb[7]);
      const bf16x8 p0a = mk8(dwa[0], dwa[1], dwa[2], dwa[3]);  // qs0, t lo16
      const bf16x8 p0b = mk8(dwa[4], dwa[5], dwa[6], dwa[7]);  // qs0, t hi16
      const bf16x8 p1a = mk8(dwb[0], dwb[1], dwb[2], dwb[3]);
      const bf16x8 p1b = mk8(dwb[4], dwb[5], dwb[6], dwb[7]);

      // ---- V fragments (reused by both q-subtiles) ----
      bf16x8 v0a = *(const bf16x8*)&Vp[(l31) * KPAD + (tt * 2 + 0) * 16 + hi * 8];
      bf16x8 v0b = *(const bf16x8*)&Vp[(l31) * KPAD + (tt * 2 + 1) * 16 + hi * 8];
      bf16x8 v1a = *(const bf16x8*)&Vp[(32 + l31) * KPAD + (tt * 2 + 0) * 16 + hi * 8];
      bf16x8 v1b = *(const bf16x8*)&Vp[(32 + l31) * KPAD + (tt * 2 + 1) * 16 + hi * 8];

      // ---- O^T += V^T P^T ----
      __builtin_amdgcn_s_setprio(1);
      o00 = __builtin_amdgcn_mfma_f32_32x32x16_bf16(v0a, p0a, o00, 0, 0, 0);
      o00 = __builtin_amdgcn_mfma_f32_32x32x16_bf16(v0b, p0b, o00, 0, 0, 0);
      o01 = __builtin_amdgcn_mfma_f32_32x32x16_bf16(v1a, p0a, o01, 0, 0, 0);
      o01 = __builtin_amdgcn_mfma_f32_32x32x16_bf16(v1b, p0b, o01, 0, 0, 0);
      o10 = __builtin_amdgcn_mfma_f32_32x32x16_bf16(v0a, p1a, o10, 0, 0, 0);
      o10 = __builtin_amdgcn_mfma_f32_32x32x16_bf16(v0b, p1b, o10, 0, 0, 0);
      o11 = __builtin_amdgcn_mfma_f32_32x32x16_bf16(v1a, p1a, o11, 0, 0, 0);
      o11 = __builtin_amdgcn_mfma_f32_32x32x16_bf16(v1b, p1b, o11, 0, 0, 0);
      __builtin_amdgcn_s_setprio(0);
    }

    if (c < 31) {  // write staged regs into the other buffer
#pragma unroll
      for (int i = 0; i < 4; ++i) {
        *(bf16x8*)&Ks[p ^ 1][lofs + i * 8] = kst[i];
        *(bf16x8*)&Vs[p ^ 1][lofs + i * 8] = vst[i];
      }
    }
    __syncthreads();
  }

  // ---- l: add the other 32-lane half's partial (per q-subtile) ----
  unsigned la0 = __builtin_bit_cast(unsigned, l0), lb0 = la0;
  PLSWAP(la0, lb0);
  const float l0t = l0 + __builtin_bit_cast(float, hi ? la0 : lb0);
  unsigned la1 = __builtin_bit_cast(unsigned, l1), lb1 = la1;
  PLSWAP(la1, lb1);
  const float l1t = l1 + __builtin_bit_cast(float, hi ? la1 : lb1);

  // ---- epilogue: O^T regs are 4-d-contiguous -> b64 Y stores ----
  const int b = bh / 12;
  const int head = bh - b * 12;
#pragma unroll
  for (int qs = 0; qs < 2; ++qs) {
    const float rl = 1.0f / (qs ? l1t : l0t);
    const int row = qt * 128 + wv * 64 + qs * 32 + l31;
    unsigned short* yb = Y + ((size_t)(b * 2048 + row)) * 768 + head * 64;
#pragma unroll
    for (int dt = 0; dt < 2; ++dt) {
      const f32x16& oo = qs ? (dt ? o11 : o10) : (dt ? o01 : o00);
#pragma unroll
      for (int g4 = 0; g4 < 4; ++g4) {
        const int d = dt * 32 + g4 * 8 + hi * 4;
        const unsigned long long pk =
            (unsigned long long)pk2(oo[g4 * 4 + 0] * rl, oo[g4 * 4 + 1] * rl) |
            ((unsigned long long)pk2(oo[g4 * 4 + 2] * rl, oo[g4 * 4 + 3] * rl) << 32);
        *(unsigned long long*)(yb + d) = pk;
      }
    }
  }
}

// ---------------------------------------------------------------------------
extern "C" void kernel_launch(void* const* d_in, const int* in_sizes, int n_in,
                              void* d_out, int out_size, void* d_ws, size_t ws_size,
                              hipStream_t stream) {
  const float* x      = (const float*)d_in[0];
  const float* w_attn = (const float*)d_in[1];
  const float* b_attn = (const float*)d_in[2];
  const float* w_proj = (const float*)d_in[3];
  const float* b_proj = (const float*)d_in[4];
  const float* ln_g[2] = {(const float*)d_in[5], (const float*)d_in[7]};
  const float* ln_b[2] = {(const float*)d_in[6], (const float*)d_in[8]};
  float* out = (float*)d_out;

  unsigned short* wAt = (unsigned short*)d_ws;     // (2304,768) bf16
  unsigned short* wPt = wAt + 2304 * 768;          // (768,768)  bf16
  unsigned short* h   = wPt + 768 * 768;           // (8192,768) bf16
  unsigned short* q   = h + 8192 * 768;            // (48,2048,64)
  unsigned short* k   = q + 48 * 2048 * 64;
  unsigned short* vt  = k + 48 * 2048 * 64;        // (48,64,2048) = V^T
  unsigned short* y   = vt + 48 * 2048 * 64;       // (8192,768) bf16

  wt_kernel<<<dim3(72, 24), dim3(32, 8), 0, stream>>>(w_attn, wAt, 2304);
  wt_kernel<<<dim3(24, 24), dim3(32, 8), 0, stream>>>(w_proj, wPt, 768);

  for (int pass = 0; pass < 2; ++pass) {
    const float* xin = pass ? (const float*)out : x;
    ln_kernel<<<8192, 256, 0, stream>>>(xin, ln_g[pass], ln_b[pass], h);
    gemm_kernel<0><<<dim3(18, 64), 256, 0, stream>>>(h, wAt, b_attn, nullptr,
                                                     q, k, vt, nullptr);
    attn_kernel<<<dim3(48, 16), dim3(128), 0, stream>>>(q, k, vt, y);
    gemm_kernel<1><<<dim3(6, 64), 256, 0, stream>>>(y, wPt, b_proj, xin,
                                                    nullptr, nullptr, nullptr, out);
  }
}

// Round 5
// 394.456 us; speedup vs baseline: 1.1647x; 1.1647x over previous
//
#include <hip/hip_runtime.h>

// ---------------------------------------------------------------------------
// Block = x + attn(ln1(x)); x = x + attn(ln2(x))   (attn twice, no MLP,
// no causal mask, softmax scale = C^-0.5).  B=4 T=2048 C=768 H=12 hd=64.
// R15 = R12 restored byte-exact (R12 passed: total 386.6us, attn 71.0us)
// with ONE change: attn __launch_bounds__(256,3) -> (256,4).  LDS 32KB/block
// -> 4 blocks/CU = 16 waves/CU (was 12); VGPR 68 << 128 cap, no spill risk.
// R13/R14's reg-staged PAD-68 path is retired: R14 failed correctness in a
// way not explained by inspection -> revert to the verified staging.
// attn body: 32x32x16 MFMA, in-register P via permlane32_swap, K/V via
// swizzled global_load_lds dbuf, 1 barrier/chunk, VALU l, fixed-max softmax.
// ---------------------------------------------------------------------------

using bf16x8 = __attribute__((ext_vector_type(8))) short;   // 8 bf16 = 4 VGPRs
using f32x4  = __attribute__((ext_vector_type(4))) float;
using f32x16 = __attribute__((ext_vector_type(16))) float;

__device__ __forceinline__ unsigned short f2b(float f) {
  unsigned u = __builtin_bit_cast(unsigned, f);
  u += 0x7FFFu + ((u >> 16) & 1u);          // RNE
  return (unsigned short)(u >> 16);
}
// pack two floats -> two bf16 (RNE) in one dword: lo=a, hi=b
__device__ __forceinline__ unsigned pk2(float a, float b) {
  unsigned ua = __builtin_bit_cast(unsigned, a);
  ua += 0x7FFFu + ((ua >> 16) & 1u);
  unsigned ub = __builtin_bit_cast(unsigned, b);
  ub += 0x7FFFu + ((ub >> 16) & 1u);
  return (ua >> 16) | (ub & 0xFFFF0000u);
}

__device__ __forceinline__ bf16x8 mk8(unsigned a, unsigned b, unsigned c,
                                      unsigned d) {
  union { unsigned u[4]; bf16x8 v; } x;
  x.u[0] = a; x.u[1] = b; x.u[2] = c; x.u[3] = d;
  return x.v;
}

#define ASYNC16(g, l)                                                        \
  __builtin_amdgcn_global_load_lds(                                          \
      (const __attribute__((address_space(1))) void*)(g),                    \
      (__attribute__((address_space(3))) void*)(l), 16, 0, 0)

// swap a.hi32lanes <-> b.lo32lanes (V_PERMLANE32_SWAP_B32)
#define PLSWAP(a, b) asm("v_permlane32_swap_b32 %0, %1" : "+v"(a), "+v"(b))

// ---------------------------------------------------------------------------
// Weight transpose+cast: w (768, N) fp32  ->  wt (N, 768) bf16
// ---------------------------------------------------------------------------
__global__ __launch_bounds__(256) void wt_kernel(const float* __restrict__ w,
                                                 unsigned short* __restrict__ wt,
                                                 int N) {
  __shared__ float tile[32][33];
  const int n0 = blockIdx.x * 32, k0 = blockIdx.y * 32;
  const int tx = threadIdx.x, ty = threadIdx.y;  // (32, 8)
#pragma unroll
  for (int i = 0; i < 32; i += 8)
    tile[ty + i][tx] = w[(size_t)(k0 + ty + i) * N + n0 + tx];
  __syncthreads();
#pragma unroll
  for (int i = 0; i < 32; i += 8)
    wt[(size_t)(n0 + ty + i) * 768 + k0 + tx] = f2b(tile[tx][ty + i]);
}

// ---------------------------------------------------------------------------
// LayerNorm: x (8192, 768) fp32 -> h bf16.  One block per row.
// ---------------------------------------------------------------------------
__global__ __launch_bounds__(256) void ln_kernel(const float* __restrict__ x,
                                                 const float* __restrict__ g,
                                                 const float* __restrict__ b,
                                                 unsigned short* __restrict__ h) {
  __shared__ float red[8];
  const int row = blockIdx.x;
  const int tid = threadIdx.x;
  const float* xr = x + (size_t)row * 768;
  float v0 = xr[tid], v1 = xr[tid + 256], v2 = xr[tid + 512];
  float s = v0 + v1 + v2;
  float s2 = v0 * v0 + v1 * v1 + v2 * v2;
#pragma unroll
  for (int off = 1; off < 64; off <<= 1) {
    s += __shfl_xor(s, off);
    s2 += __shfl_xor(s2, off);
  }
  if ((tid & 63) == 0) { red[tid >> 6] = s; red[4 + (tid >> 6)] = s2; }
  __syncthreads();
  const float S  = red[0] + red[1] + red[2] + red[3];
  const float S2 = red[4] + red[5] + red[6] + red[7];
  const float mu  = S * (1.0f / 768.0f);
  const float var = S2 * (1.0f / 768.0f) - mu * mu;
  const float inv = rsqrtf(var + 1e-5f);
  unsigned short* hr = h + (size_t)row * 768;
  hr[tid]       = f2b((v0 - mu) * inv * g[tid] + b[tid]);
  hr[tid + 256] = f2b((v1 - mu) * inv * g[tid + 256] + b[tid + 256]);
  hr[tid + 512] = f2b((v2 - mu) * inv * g[tid + 512] + b[tid + 512]);
}

// ---------------------------------------------------------------------------
// bf16 GEMM, m97 pattern: A (M,768) bf16 row-major, Bt (N,768) bf16,
// 128x128 tile, BK=32, 4 waves x 4x4 mfma tiles.
// EPI 0: scatter qkv (+bias): q (scaled by c2), k -> (bh,t,d) b16 stores;
//        v -> V^T (bh,d,t) with PACKED b64 stores (r values are t-contig).
// EPI 1: out fp32 = resid + bias + acc.
// ---------------------------------------------------------------------------
template <int EPI>
__global__ __launch_bounds__(256, 2) void gemm_kernel(
    const unsigned short* __restrict__ A, const unsigned short* __restrict__ Bt,
    const float* __restrict__ bias, const float* __restrict__ resid,
    unsigned short* __restrict__ q, unsigned short* __restrict__ k,
    unsigned short* __restrict__ vt, float* __restrict__ outF) {
  __shared__ alignas(16) unsigned short As[128 * 32];
  __shared__ alignas(16) unsigned short Bs[128 * 32];

  const int tid = threadIdx.x;
  const int wv = tid >> 6;
  const int lane = tid & 63;
  const int quad = lane >> 4;
  const int l15 = lane & 15;
  const int m0 = blockIdx.y * 128;
  const int n0 = blockIdx.x * 128;

  const int o0 = wv * 1024 + lane * 16;
  const int rT0 = o0 >> 6, c0 = (o0 & 63) >> 1;
  const int o1 = o0 + 4096;
  const int rT1 = o1 >> 6, c1 = (o1 & 63) >> 1;

  const unsigned short* gA0 = A + (size_t)(m0 + rT0) * 768 + c0;
  const unsigned short* gA1 = A + (size_t)(m0 + rT1) * 768 + c1;
  const unsigned short* gB0 = Bt + (size_t)(n0 + rT0) * 768 + c0;
  const unsigned short* gB1 = Bt + (size_t)(n0 + rT1) * 768 + c1;
  unsigned short* lA0 = &As[wv * 512];
  unsigned short* lA1 = &As[wv * 512 + 2048];
  unsigned short* lB0 = &Bs[wv * 512];
  unsigned short* lB1 = &Bs[wv * 512 + 2048];

  f32x4 acc[4][4];
#pragma unroll
  for (int i = 0; i < 4; ++i)
#pragma unroll
    for (int j = 0; j < 4; ++j) acc[i][j] = {0.f, 0.f, 0.f, 0.f};

  const int mBase = (wv >> 1) * 64;
  const int nBase = (wv & 1) * 64;

  for (int kk = 0; kk < 24; ++kk) {
    const int ko = kk * 32;
    ASYNC16(gA0 + ko, lA0);
    ASYNC16(gA1 + ko, lA1);
    ASYNC16(gB0 + ko, lB0);
    ASYNC16(gB1 + ko, lB1);
    __syncthreads();
    bf16x8 af[4], bfv[4];
#pragma unroll
    for (int mt = 0; mt < 4; ++mt)
      af[mt] = *(const bf16x8*)&As[(mBase + mt * 16 + l15) * 32 + quad * 8];
#pragma unroll
    for (int nt = 0; nt < 4; ++nt)
      bfv[nt] = *(const bf16x8*)&Bs[(nBase + nt * 16 + l15) * 32 + quad * 8];
#pragma unroll
    for (int mt = 0; mt < 4; ++mt)
#pragma unroll
      for (int nt = 0; nt < 4; ++nt)
        acc[mt][nt] = __builtin_amdgcn_mfma_f32_16x16x32_bf16(af[mt], bfv[nt],
                                                              acc[mt][nt], 0, 0, 0);
    __syncthreads();
  }

  if constexpr (EPI == 0) {
    const float c2 = 0.052062786090587f;  // 768^-0.5 * log2(e), folded into Q
#pragma unroll
    for (int mt = 0; mt < 4; ++mt) {
#pragma unroll
      for (int nt = 0; nt < 4; ++nt) {
        const int n = n0 + nBase + nt * 16 + l15;
        const int head = n / 192;
        const int rem = n - head * 192;
        const int sel = rem >> 6;
        const int d = rem & 63;
        const float bv = bias[n];
        const int mr = m0 + mBase + mt * 16 + quad * 4;   // r=0 row
        const int bb = mr >> 11;
        const int t = mr & 2047;
        if (sel == 2) {
          // V^T (bh,d,t): 4 r-values are t-contiguous -> one b64 store
          const unsigned long long pk =
              (unsigned long long)pk2(acc[mt][nt][0] + bv, acc[mt][nt][1] + bv) |
              ((unsigned long long)pk2(acc[mt][nt][2] + bv, acc[mt][nt][3] + bv) << 32);
          *(unsigned long long*)&vt[(((size_t)bb * 12 + head) * 64 + d) * 2048 + t] = pk;
        } else {
          unsigned short* tgt = (sel == 0) ? q : k;
          const float sc = (sel == 0) ? c2 : 1.0f;
#pragma unroll
          for (int r = 0; r < 4; ++r)
            tgt[(((size_t)bb * 12 + head) * 2048 + t + r) * 64 + d] =
                f2b((acc[mt][nt][r] + bv) * sc);
        }
      }
    }
  } else {
#pragma unroll
    for (int mt = 0; mt < 4; ++mt) {
#pragma unroll
      for (int nt = 0; nt < 4; ++nt) {
        const int n = n0 + nBase + nt * 16 + l15;
        const float bv = bias[n];
#pragma unroll
        for (int r = 0; r < 4; ++r) {
          const int m = m0 + mBase + mt * 16 + quad * 4 + r;
          const size_t idx = (size_t)m * 768 + n;
          outF[idx] = resid[idx] + bv + acc[mt][nt][r];
        }
      }
    }
  }
}

// ---------------------------------------------------------------------------
// Flash attention (R12 body, verified): 32x32x16 MFMA, in-register P via
// permlane swaps, K/V via swizzled global_load_lds dbuf, 1 barrier/chunk.
//   S^T = K Q^T (Q pre-scaled by c2) -> P = exp2(S^T) truncated to bf16 in
//   regs -> O^T += V^T P^T ;  l += sum(P) in VALU.  Fixed-max softmax.
// Per wave: 32 q rows, chunk = 64 t.  Block: 4 waves = 128 q.
// Only change vs R12: launch_bounds (256,3)->(256,4): LDS 32KB -> 4 blk/CU.
// ---------------------------------------------------------------------------
__global__ __launch_bounds__(256, 4) void attn_kernel(
    const unsigned short* __restrict__ Q, const unsigned short* __restrict__ Km,
    const unsigned short* __restrict__ Vt, unsigned short* __restrict__ Y) {
  __shared__ alignas(16) unsigned short Ks[2][64 * 64];  // [t][d], swizzled
  __shared__ alignas(16) unsigned short Vs[2][64 * 64];  // [d][t], swizzled

  const int bh   = blockIdx.x;
  const int qt   = blockIdx.y;
  const int tid  = threadIdx.x;
  const int wv   = tid >> 6;
  const int lane = tid & 63;
  const int l31  = lane & 31;
  const int hi   = lane >> 5;
  const int s7   = l31 & 7;
  const size_t bhT = (size_t)bh * 2048;

  // ---- Q fragments: B-operand, lane holds Q[q=l31][d=ks*16+hi*8+j] --------
  bf16x8 qf[4];
  {
    const unsigned short* qb =
        Q + (bhT + qt * 128 + wv * 32 + l31) * 64 + hi * 8;
#pragma unroll
    for (int ks = 0; ks < 4; ++ks) qf[ks] = *(const bf16x8*)(qb + ks * 16);
  }

  // ---- staging: linear LDS dest, inverse-swizzled global source -----------
  // LDS slot L (bytes): row r = L>>7, in-row byte = (L&127) ^ ((r&7)<<4)
  const int L0 = wv * 1024 + (lane << 4);
  const int L1 = L0 + 4096;
  const int r0 = L0 >> 7, b0 = (L0 & 127) ^ ((r0 & 7) << 4);
  const int r1 = L1 >> 7, b1 = (L1 & 127) ^ ((r1 & 7) << 4);
  const unsigned short* kg0 = Km + (bhT + r0) * 64 + (b0 >> 1);
  const unsigned short* kg1 = Km + (bhT + r1) * 64 + (b1 >> 1);
  const unsigned short* vg0 = Vt + ((size_t)bh * 64 + r0) * 2048 + (b0 >> 1);
  const unsigned short* vg1 = Vt + ((size_t)bh * 64 + r1) * 2048 + (b1 >> 1);
  const int kb0 = wv * 512, kb1 = wv * 512 + 2048;  // ushort units

  f32x16 o0, o1;
#pragma unroll
  for (int i = 0; i < 16; ++i) { o0[i] = 0.f; o1[i] = 0.f; }
  float l_acc = 0.f;

  // prologue: stage chunk 0 into buf 0
  ASYNC16(kg0, &Ks[0][kb0]);
  ASYNC16(kg1, &Ks[0][kb1]);
  ASYNC16(vg0, &Vs[0][kb0]);
  ASYNC16(vg1, &Vs[0][kb1]);
  __syncthreads();

  for (int c = 0; c < 32; ++c) {
    const int p = c & 1;
    if (c < 31) {  // stage c+1 into the other buffer; lands by chunk-end sync
      const int ka = (c + 1) * 4096, va = (c + 1) * 64;
      ASYNC16(kg0 + ka, &Ks[p ^ 1][kb0]);
      ASYNC16(kg1 + ka, &Ks[p ^ 1][kb1]);
      ASYNC16(vg0 + va, &Vs[p ^ 1][kb0]);
      ASYNC16(vg1 + va, &Vs[p ^ 1][kb1]);
    }
    const unsigned short* Kp = &Ks[p][0];
    const unsigned short* Vp = &Vs[p][0];

#pragma unroll
    for (int tt = 0; tt < 2; ++tt) {
      // ---- S tile (32t x 32q): 4 chained k-steps ----
      f32x16 s;
#pragma unroll
      for (int i = 0; i < 16; ++i) s[i] = 0.f;
#pragma unroll
      for (int ks = 0; ks < 4; ++ks) {
        const int off = tt * 4096 + l31 * 128 + (((ks * 2 + hi) ^ s7) << 4);
        bf16x8 kf = *(const bf16x8*)&Kp[off >> 1];
        s = __builtin_amdgcn_mfma_f32_32x32x16_bf16(kf, qf[ks], s, 0, 0, 0);
      }

      // ---- P = exp2(S), truncate to bf16; l += truncated values ----
      unsigned dw[8];
      float lc = 0.f;
#pragma unroll
      for (int r2 = 0; r2 < 8; ++r2) {
        const float e0 = __builtin_amdgcn_exp2f(s[2 * r2]);
        const float e1 = __builtin_amdgcn_exp2f(s[2 * r2 + 1]);
        const unsigned u0 = __builtin_bit_cast(unsigned, e0) & 0xFFFF0000u;
        const unsigned u1 = __builtin_bit_cast(unsigned, e1) & 0xFFFF0000u;
        lc += __builtin_bit_cast(float, u0) + __builtin_bit_cast(float, u1);
        dw[r2] = (u0 >> 16) | u1;
      }
      l_acc += lc;

      // ---- C-layout -> B-frag: one swap yields two pf words ----
      PLSWAP(dw[0], dw[2]);
      PLSWAP(dw[1], dw[3]);
      PLSWAP(dw[4], dw[6]);
      PLSWAP(dw[5], dw[7]);
      const bf16x8 pf0 = mk8(dw[0], dw[1], dw[2], dw[3]);  // t in [tt*32, +16)
      const bf16x8 pf1 = mk8(dw[4], dw[5], dw[6], dw[7]);  // t in [+16, +32)

      // ---- O^T += V^T P^T ----
#pragma unroll
      for (int dt = 0; dt < 2; ++dt) {
        const int vb = dt * 4096 + l31 * 128;
        const int kv0 = tt * 2, kv1 = tt * 2 + 1;
        bf16x8 vf0 = *(const bf16x8*)&Vp[(vb + (((kv0 * 2 + hi) ^ s7) << 4)) >> 1];
        bf16x8 vf1 = *(const bf16x8*)&Vp[(vb + (((kv1 * 2 + hi) ^ s7) << 4)) >> 1];
        if (dt == 0) {
          o0 = __builtin_amdgcn_mfma_f32_32x32x16_bf16(vf0, pf0, o0, 0, 0, 0);
          o0 = __builtin_amdgcn_mfma_f32_32x32x16_bf16(vf1, pf1, o0, 0, 0, 0);
        } else {
          o1 = __builtin_amdgcn_mfma_f32_32x32x16_bf16(vf0, pf0, o1, 0, 0, 0);
          o1 = __builtin_amdgcn_mfma_f32_32x32x16_bf16(vf1, pf1, o1, 0, 0, 0);
        }
      }
    }
    __syncthreads();  // waits vmcnt (next-chunk stages landed) + all waves
  }

  // ---- l: add the other 32-lane half's partial ----
  unsigned la = __builtin_bit_cast(unsigned, l_acc), lb = la;
  PLSWAP(la, lb);
  // lanes<32: other half's value is in lb; lanes>=32: in la
  const float l_tot =
      l_acc + __builtin_bit_cast(float, hi ? la : lb);
  const float rl = 1.0f / l_tot;

  // ---- epilogue: O^T regs are 4-d-contiguous -> b64 Y stores ----
  const int b = bh / 12;
  const int head = bh - b * 12;
  const int row = qt * 128 + wv * 32 + l31;
  unsigned short* yb = Y + ((size_t)(b * 2048 + row)) * 768 + head * 64;
#pragma unroll
  for (int dt = 0; dt < 2; ++dt) {
    const f32x16& oo = dt ? o1 : o0;
#pragma unroll
    for (int g4 = 0; g4 < 4; ++g4) {
      const int d = dt * 32 + g4 * 8 + hi * 4;
      const float a0 = oo[g4 * 4 + 0] * rl;
      const float a1 = oo[g4 * 4 + 1] * rl;
      const float a2 = oo[g4 * 4 + 2] * rl;
      const float a3 = oo[g4 * 4 + 3] * rl;
      const unsigned long long pk =
          (unsigned long long)pk2(a0, a1) | ((unsigned long long)pk2(a2, a3) << 32);
      *(unsigned long long*)(yb + d) = pk;
    }
  }
}

// ---------------------------------------------------------------------------
extern "C" void kernel_launch(void* const* d_in, const int* in_sizes, int n_in,
                              void* d_out, int out_size, void* d_ws, size_t ws_size,
                              hipStream_t stream) {
  const float* x      = (const float*)d_in[0];
  const float* w_attn = (const float*)d_in[1];
  const float* b_attn = (const float*)d_in[2];
  const float* w_proj = (const float*)d_in[3];
  const float* b_proj = (const float*)d_in[4];
  const float* ln_g[2] = {(const float*)d_in[5], (const float*)d_in[7]};
  const float* ln_b[2] = {(const float*)d_in[6], (const float*)d_in[8]};
  float* out = (float*)d_out;

  unsigned short* wAt = (unsigned short*)d_ws;     // (2304,768) bf16
  unsigned short* wPt = wAt + 2304 * 768;          // (768,768)  bf16
  unsigned short* h   = wPt + 768 * 768;           // (8192,768) bf16
  unsigned short* q   = h + 8192 * 768;            // (48,2048,64)
  unsigned short* k   = q + 48 * 2048 * 64;
  unsigned short* vt  = k + 48 * 2048 * 64;        // (48,64,2048) = V^T
  unsigned short* y   = vt + 48 * 2048 * 64;       // (8192,768) bf16

  wt_kernel<<<dim3(72, 24), dim3(32, 8), 0, stream>>>(w_attn, wAt, 2304);
  wt_kernel<<<dim3(24, 24), dim3(32, 8), 0, stream>>>(w_proj, wPt, 768);

  for (int pass = 0; pass < 2; ++pass) {
    const float* xin = pass ? (const float*)out : x;
    ln_kernel<<<8192, 256, 0, stream>>>(xin, ln_g[pass], ln_b[pass], h);
    gemm_kernel<0><<<dim3(18, 64), 256, 0, stream>>>(h, wAt, b_attn, nullptr,
                                                     q, k, vt, nullptr);
    attn_kernel<<<dim3(48, 16), 256, 0, stream>>>(q, k, vt, y);
    gemm_kernel<1><<<dim3(6, 64), 256, 0, stream>>>(y, wPt, b_proj, xin,
                                                    nullptr, nullptr, nullptr, out);
  }
}

// Round 6
// 385.839 us; speedup vs baseline: 1.1907x; 1.0223x over previous
//
#include <hip/hip_runtime.h>

// ---------------------------------------------------------------------------
// Block = x + attn(ln1(x)); x = x + attn(ln2(x))   (attn twice, no MLP,
// no causal mask, softmax scale = C^-0.5).  B=4 T=2048 C=768 H=12 hd=64.
// R16 = R12 (verified attn 71.0us) with:
//  - attn launch_bounds back to (256,3) (R15's (256,4) regressed: grid 768
//    = 3 blocks/CU exactly, bounds only tightened VGPR 68->64 -> 78us).
//  - attn pack: v_cvt_pk_bf16_f32 (1 op) replaces 4 bit-ops; l now sums
//    exact f32 exp values (P RNE-rounded, l unbiased; headroom 3x).
//  - gemm1 (proj): new 128x64-tile kernel, grid 12x64 = 768 blocks = 3/CU
//    (old 128x128 grid 6x64 = 384 = 1.5/CU load-imbalance).
// ---------------------------------------------------------------------------

using bf16x8 = __attribute__((ext_vector_type(8))) short;   // 8 bf16 = 4 VGPRs
using f32x4  = __attribute__((ext_vector_type(4))) float;
using f32x16 = __attribute__((ext_vector_type(16))) float;

__device__ __forceinline__ unsigned short f2b(float f) {
  unsigned u = __builtin_bit_cast(unsigned, f);
  u += 0x7FFFu + ((u >> 16) & 1u);          // RNE
  return (unsigned short)(u >> 16);
}
// pack two floats -> two bf16 (RNE) in one dword: lo=a, hi=b
__device__ __forceinline__ unsigned pk2(float a, float b) {
  unsigned ua = __builtin_bit_cast(unsigned, a);
  ua += 0x7FFFu + ((ua >> 16) & 1u);
  unsigned ub = __builtin_bit_cast(unsigned, b);
  ub += 0x7FFFu + ((ub >> 16) & 1u);
  return (ua >> 16) | (ub & 0xFFFF0000u);
}

__device__ __forceinline__ bf16x8 mk8(unsigned a, unsigned b, unsigned c,
                                      unsigned d) {
  union { unsigned u[4]; bf16x8 v; } x;
  x.u[0] = a; x.u[1] = b; x.u[2] = c; x.u[3] = d;
  return x.v;
}

#define ASYNC16(g, l)                                                        \
  __builtin_amdgcn_global_load_lds(                                          \
      (const __attribute__((address_space(1))) void*)(g),                    \
      (__attribute__((address_space(3))) void*)(l), 16, 0, 0)

// swap a.hi32lanes <-> b.lo32lanes (V_PERMLANE32_SWAP_B32)
#define PLSWAP(a, b) asm("v_permlane32_swap_b32 %0, %1" : "+v"(a), "+v"(b))

// ---------------------------------------------------------------------------
// Weight transpose+cast: w (768, N) fp32  ->  wt (N, 768) bf16
// ---------------------------------------------------------------------------
__global__ __launch_bounds__(256) void wt_kernel(const float* __restrict__ w,
                                                 unsigned short* __restrict__ wt,
                                                 int N) {
  __shared__ float tile[32][33];
  const int n0 = blockIdx.x * 32, k0 = blockIdx.y * 32;
  const int tx = threadIdx.x, ty = threadIdx.y;  // (32, 8)
#pragma unroll
  for (int i = 0; i < 32; i += 8)
    tile[ty + i][tx] = w[(size_t)(k0 + ty + i) * N + n0 + tx];
  __syncthreads();
#pragma unroll
  for (int i = 0; i < 32; i += 8)
    wt[(size_t)(n0 + ty + i) * 768 + k0 + tx] = f2b(tile[tx][ty + i]);
}

// ---------------------------------------------------------------------------
// LayerNorm: x (8192, 768) fp32 -> h bf16.  One block per row.
// ---------------------------------------------------------------------------
__global__ __launch_bounds__(256) void ln_kernel(const float* __restrict__ x,
                                                 const float* __restrict__ g,
                                                 const float* __restrict__ b,
                                                 unsigned short* __restrict__ h) {
  __shared__ float red[8];
  const int row = blockIdx.x;
  const int tid = threadIdx.x;
  const float* xr = x + (size_t)row * 768;
  float v0 = xr[tid], v1 = xr[tid + 256], v2 = xr[tid + 512];
  float s = v0 + v1 + v2;
  float s2 = v0 * v0 + v1 * v1 + v2 * v2;
#pragma unroll
  for (int off = 1; off < 64; off <<= 1) {
    s += __shfl_xor(s, off);
    s2 += __shfl_xor(s2, off);
  }
  if ((tid & 63) == 0) { red[tid >> 6] = s; red[4 + (tid >> 6)] = s2; }
  __syncthreads();
  const float S  = red[0] + red[1] + red[2] + red[3];
  const float S2 = red[4] + red[5] + red[6] + red[7];
  const float mu  = S * (1.0f / 768.0f);
  const float var = S2 * (1.0f / 768.0f) - mu * mu;
  const float inv = rsqrtf(var + 1e-5f);
  unsigned short* hr = h + (size_t)row * 768;
  hr[tid]       = f2b((v0 - mu) * inv * g[tid] + b[tid]);
  hr[tid + 256] = f2b((v1 - mu) * inv * g[tid + 256] + b[tid + 256]);
  hr[tid + 512] = f2b((v2 - mu) * inv * g[tid + 512] + b[tid + 512]);
}

// ---------------------------------------------------------------------------
// bf16 GEMM (qkv), m97 pattern: A (M,768) bf16 row-major, Bt (N,768) bf16,
// 128x128 tile, BK=32, 4 waves x 4x4 mfma tiles.
// EPI: scatter qkv (+bias): q (scaled by c2), k -> (bh,t,d) b16 stores;
//      v -> V^T (bh,d,t) with PACKED b64 stores (r values are t-contig).
// ---------------------------------------------------------------------------
__global__ __launch_bounds__(256, 2) void gemm_kernel(
    const unsigned short* __restrict__ A, const unsigned short* __restrict__ Bt,
    const float* __restrict__ bias,
    unsigned short* __restrict__ q, unsigned short* __restrict__ k,
    unsigned short* __restrict__ vt) {
  __shared__ alignas(16) unsigned short As[128 * 32];
  __shared__ alignas(16) unsigned short Bs[128 * 32];

  const int tid = threadIdx.x;
  const int wv = tid >> 6;
  const int lane = tid & 63;
  const int quad = lane >> 4;
  const int l15 = lane & 15;
  const int m0 = blockIdx.y * 128;
  const int n0 = blockIdx.x * 128;

  const int o0 = wv * 1024 + lane * 16;
  const int rT0 = o0 >> 6, c0 = (o0 & 63) >> 1;
  const int o1 = o0 + 4096;
  const int rT1 = o1 >> 6, c1 = (o1 & 63) >> 1;

  const unsigned short* gA0 = A + (size_t)(m0 + rT0) * 768 + c0;
  const unsigned short* gA1 = A + (size_t)(m0 + rT1) * 768 + c1;
  const unsigned short* gB0 = Bt + (size_t)(n0 + rT0) * 768 + c0;
  const unsigned short* gB1 = Bt + (size_t)(n0 + rT1) * 768 + c1;
  unsigned short* lA0 = &As[wv * 512];
  unsigned short* lA1 = &As[wv * 512 + 2048];
  unsigned short* lB0 = &Bs[wv * 512];
  unsigned short* lB1 = &Bs[wv * 512 + 2048];

  f32x4 acc[4][4];
#pragma unroll
  for (int i = 0; i < 4; ++i)
#pragma unroll
    for (int j = 0; j < 4; ++j) acc[i][j] = {0.f, 0.f, 0.f, 0.f};

  const int mBase = (wv >> 1) * 64;
  const int nBase = (wv & 1) * 64;

  for (int kk = 0; kk < 24; ++kk) {
    const int ko = kk * 32;
    ASYNC16(gA0 + ko, lA0);
    ASYNC16(gA1 + ko, lA1);
    ASYNC16(gB0 + ko, lB0);
    ASYNC16(gB1 + ko, lB1);
    __syncthreads();
    bf16x8 af[4], bfv[4];
#pragma unroll
    for (int mt = 0; mt < 4; ++mt)
      af[mt] = *(const bf16x8*)&As[(mBase + mt * 16 + l15) * 32 + quad * 8];
#pragma unroll
    for (int nt = 0; nt < 4; ++nt)
      bfv[nt] = *(const bf16x8*)&Bs[(nBase + nt * 16 + l15) * 32 + quad * 8];
#pragma unroll
    for (int mt = 0; mt < 4; ++mt)
#pragma unroll
      for (int nt = 0; nt < 4; ++nt)
        acc[mt][nt] = __builtin_amdgcn_mfma_f32_16x16x32_bf16(af[mt], bfv[nt],
                                                              acc[mt][nt], 0, 0, 0);
    __syncthreads();
  }

  const float c2 = 0.052062786090587f;  // 768^-0.5 * log2(e), folded into Q
#pragma unroll
  for (int mt = 0; mt < 4; ++mt) {
#pragma unroll
    for (int nt = 0; nt < 4; ++nt) {
      const int n = n0 + nBase + nt * 16 + l15;
      const int head = n / 192;
      const int rem = n - head * 192;
      const int sel = rem >> 6;
      const int d = rem & 63;
      const float bv = bias[n];
      const int mr = m0 + mBase + mt * 16 + quad * 4;   // r=0 row
      const int bb = mr >> 11;
      const int t = mr & 2047;
      if (sel == 2) {
        // V^T (bh,d,t): 4 r-values are t-contiguous -> one b64 store
        const unsigned long long pk =
            (unsigned long long)pk2(acc[mt][nt][0] + bv, acc[mt][nt][1] + bv) |
            ((unsigned long long)pk2(acc[mt][nt][2] + bv, acc[mt][nt][3] + bv) << 32);
        *(unsigned long long*)&vt[(((size_t)bb * 12 + head) * 64 + d) * 2048 + t] = pk;
      } else {
        unsigned short* tgt = (sel == 0) ? q : k;
        const float sc = (sel == 0) ? c2 : 1.0f;
#pragma unroll
        for (int r = 0; r < 4; ++r)
          tgt[(((size_t)bb * 12 + head) * 2048 + t + r) * 64 + d] =
              f2b((acc[mt][nt][r] + bv) * sc);
      }
    }
  }
}

// ---------------------------------------------------------------------------
// Proj GEMM: 128x64 tile (grid 12x64 = 768 blocks = 3/CU; old 128x128 was
// 384 blocks = 1.5/CU imbalance).  4 waves in 2x2: each 64m x 32n, acc[4][2].
// out fp32 = resid + bias + acc.
// ---------------------------------------------------------------------------
__global__ __launch_bounds__(256, 3) void gemm1_kernel(
    const unsigned short* __restrict__ A, const unsigned short* __restrict__ Bt,
    const float* __restrict__ bias, const float* __restrict__ resid,
    float* __restrict__ outF) {
  __shared__ alignas(16) unsigned short As[128 * 32];
  __shared__ alignas(16) unsigned short Bs[64 * 32];

  const int tid = threadIdx.x;
  const int wv = tid >> 6;
  const int lane = tid & 63;
  const int quad = lane >> 4;
  const int l15 = lane & 15;
  const int m0 = blockIdx.y * 128;
  const int n0 = blockIdx.x * 64;

  const int o0 = wv * 1024 + lane * 16;
  const int rT0 = o0 >> 6, c0 = (o0 & 63) >> 1;
  const int o1 = o0 + 4096;
  const int rT1 = o1 >> 6, c1 = (o1 & 63) >> 1;

  const unsigned short* gA0 = A + (size_t)(m0 + rT0) * 768 + c0;
  const unsigned short* gA1 = A + (size_t)(m0 + rT1) * 768 + c1;
  const unsigned short* gB0 = Bt + (size_t)(n0 + rT0) * 768 + c0;
  unsigned short* lA0 = &As[wv * 512];
  unsigned short* lA1 = &As[wv * 512 + 2048];
  unsigned short* lB0 = &Bs[wv * 512];

  f32x4 acc[4][2];
#pragma unroll
  for (int i = 0; i < 4; ++i)
#pragma unroll
    for (int j = 0; j < 2; ++j) acc[i][j] = {0.f, 0.f, 0.f, 0.f};

  const int mBase = (wv >> 1) * 64;
  const int nBase = (wv & 1) * 32;

  for (int kk = 0; kk < 24; ++kk) {
    const int ko = kk * 32;
    ASYNC16(gA0 + ko, lA0);
    ASYNC16(gA1 + ko, lA1);
    ASYNC16(gB0 + ko, lB0);
    __syncthreads();
    bf16x8 af[4], bfv[2];
#pragma unroll
    for (int mt = 0; mt < 4; ++mt)
      af[mt] = *(const bf16x8*)&As[(mBase + mt * 16 + l15) * 32 + quad * 8];
#pragma unroll
    for (int nt = 0; nt < 2; ++nt)
      bfv[nt] = *(const bf16x8*)&Bs[(nBase + nt * 16 + l15) * 32 + quad * 8];
#pragma unroll
    for (int mt = 0; mt < 4; ++mt)
#pragma unroll
      for (int nt = 0; nt < 2; ++nt)
        acc[mt][nt] = __builtin_amdgcn_mfma_f32_16x16x32_bf16(af[mt], bfv[nt],
                                                              acc[mt][nt], 0, 0, 0);
    __syncthreads();
  }

#pragma unroll
  for (int mt = 0; mt < 4; ++mt) {
#pragma unroll
    for (int nt = 0; nt < 2; ++nt) {
      const int n = n0 + nBase + nt * 16 + l15;
      const float bv = bias[n];
#pragma unroll
      for (int r = 0; r < 4; ++r) {
        const int m = m0 + mBase + mt * 16 + quad * 4 + r;
        const size_t idx = (size_t)m * 768 + n;
        outF[idx] = resid[idx] + bv + acc[mt][nt][r];
      }
    }
  }
}

// ---------------------------------------------------------------------------
// Flash attention (R12 body, verified 71.0us): 32x32x16 MFMA, in-register P
// via permlane swaps, K/V via swizzled global_load_lds dbuf, 1 barrier/chunk.
//   S^T = K Q^T (Q pre-scaled by c2) -> P = exp2(S^T) -> bf16 via
//   v_cvt_pk_bf16_f32 -> O^T += V^T P^T ;  l += exact f32 exp sum (VALU).
// Per wave: 32 q rows, chunk = 64 t.  Block: 4 waves = 128 q.
// ---------------------------------------------------------------------------
__global__ __launch_bounds__(256, 3) void attn_kernel(
    const unsigned short* __restrict__ Q, const unsigned short* __restrict__ Km,
    const unsigned short* __restrict__ Vt, unsigned short* __restrict__ Y) {
  __shared__ alignas(16) unsigned short Ks[2][64 * 64];  // [t][d], swizzled
  __shared__ alignas(16) unsigned short Vs[2][64 * 64];  // [d][t], swizzled

  const int bh   = blockIdx.x;
  const int qt   = blockIdx.y;
  const int tid  = threadIdx.x;
  const int wv   = tid >> 6;
  const int lane = tid & 63;
  const int l31  = lane & 31;
  const int hi   = lane >> 5;
  const int s7   = l31 & 7;
  const size_t bhT = (size_t)bh * 2048;

  // ---- Q fragments: B-operand, lane holds Q[q=l31][d=ks*16+hi*8+j] --------
  bf16x8 qf[4];
  {
    const unsigned short* qb =
        Q + (bhT + qt * 128 + wv * 32 + l31) * 64 + hi * 8;
#pragma unroll
    for (int ks = 0; ks < 4; ++ks) qf[ks] = *(const bf16x8*)(qb + ks * 16);
  }

  // ---- staging: linear LDS dest, inverse-swizzled global source -----------
  // LDS slot L (bytes): row r = L>>7, in-row byte = (L&127) ^ ((r&7)<<4)
  const int L0 = wv * 1024 + (lane << 4);
  const int L1 = L0 + 4096;
  const int r0 = L0 >> 7, b0 = (L0 & 127) ^ ((r0 & 7) << 4);
  const int r1 = L1 >> 7, b1 = (L1 & 127) ^ ((r1 & 7) << 4);
  const unsigned short* kg0 = Km + (bhT + r0) * 64 + (b0 >> 1);
  const unsigned short* kg1 = Km + (bhT + r1) * 64 + (b1 >> 1);
  const unsigned short* vg0 = Vt + ((size_t)bh * 64 + r0) * 2048 + (b0 >> 1);
  const unsigned short* vg1 = Vt + ((size_t)bh * 64 + r1) * 2048 + (b1 >> 1);
  const int kb0 = wv * 512, kb1 = wv * 512 + 2048;  // ushort units

  f32x16 o0, o1;
#pragma unroll
  for (int i = 0; i < 16; ++i) { o0[i] = 0.f; o1[i] = 0.f; }
  float l_acc = 0.f;

  // prologue: stage chunk 0 into buf 0
  ASYNC16(kg0, &Ks[0][kb0]);
  ASYNC16(kg1, &Ks[0][kb1]);
  ASYNC16(vg0, &Vs[0][kb0]);
  ASYNC16(vg1, &Vs[0][kb1]);
  __syncthreads();

  for (int c = 0; c < 32; ++c) {
    const int p = c & 1;
    if (c < 31) {  // stage c+1 into the other buffer; lands by chunk-end sync
      const int ka = (c + 1) * 4096, va = (c + 1) * 64;
      ASYNC16(kg0 + ka, &Ks[p ^ 1][kb0]);
      ASYNC16(kg1 + ka, &Ks[p ^ 1][kb1]);
      ASYNC16(vg0 + va, &Vs[p ^ 1][kb0]);
      ASYNC16(vg1 + va, &Vs[p ^ 1][kb1]);
    }
    const unsigned short* Kp = &Ks[p][0];
    const unsigned short* Vp = &Vs[p][0];

#pragma unroll
    for (int tt = 0; tt < 2; ++tt) {
      // ---- S tile (32t x 32q): 4 chained k-steps ----
      f32x16 s;
#pragma unroll
      for (int i = 0; i < 16; ++i) s[i] = 0.f;
#pragma unroll
      for (int ks = 0; ks < 4; ++ks) {
        const int off = tt * 4096 + l31 * 128 + (((ks * 2 + hi) ^ s7) << 4);
        bf16x8 kf = *(const bf16x8*)&Kp[off >> 1];
        s = __builtin_amdgcn_mfma_f32_32x32x16_bf16(kf, qf[ks], s, 0, 0, 0);
      }

      // ---- P = exp2(S) -> bf16 (cvt_pk, RNE); l += exact f32 sum ----
      unsigned dw[8];
      float lc = 0.f;
#pragma unroll
      for (int r2 = 0; r2 < 8; ++r2) {
        const float e0 = __builtin_amdgcn_exp2f(s[2 * r2]);
        const float e1 = __builtin_amdgcn_exp2f(s[2 * r2 + 1]);
        lc += e0 + e1;
        asm("v_cvt_pk_bf16_f32 %0, %1, %2" : "=v"(dw[r2]) : "v"(e0), "v"(e1));
      }
      l_acc += lc;

      // ---- C-layout -> B-frag: one swap yields two pf words ----
      PLSWAP(dw[0], dw[2]);
      PLSWAP(dw[1], dw[3]);
      PLSWAP(dw[4], dw[6]);
      PLSWAP(dw[5], dw[7]);
      const bf16x8 pf0 = mk8(dw[0], dw[1], dw[2], dw[3]);  // t in [tt*32, +16)
      const bf16x8 pf1 = mk8(dw[4], dw[5], dw[6], dw[7]);  // t in [+16, +32)

      // ---- O^T += V^T P^T ----
#pragma unroll
      for (int dt = 0; dt < 2; ++dt) {
        const int vb = dt * 4096 + l31 * 128;
        const int kv0 = tt * 2, kv1 = tt * 2 + 1;
        bf16x8 vf0 = *(const bf16x8*)&Vp[(vb + (((kv0 * 2 + hi) ^ s7) << 4)) >> 1];
        bf16x8 vf1 = *(const bf16x8*)&Vp[(vb + (((kv1 * 2 + hi) ^ s7) << 4)) >> 1];
        if (dt == 0) {
          o0 = __builtin_amdgcn_mfma_f32_32x32x16_bf16(vf0, pf0, o0, 0, 0, 0);
          o0 = __builtin_amdgcn_mfma_f32_32x32x16_bf16(vf1, pf1, o0, 0, 0, 0);
        } else {
          o1 = __builtin_amdgcn_mfma_f32_32x32x16_bf16(vf0, pf0, o1, 0, 0, 0);
          o1 = __builtin_amdgcn_mfma_f32_32x32x16_bf16(vf1, pf1, o1, 0, 0, 0);
        }
      }
    }
    __syncthreads();  // waits vmcnt (next-chunk stages landed) + all waves
  }

  // ---- l: add the other 32-lane half's partial ----
  unsigned la = __builtin_bit_cast(unsigned, l_acc), lb = la;
  PLSWAP(la, lb);
  // lanes<32: other half's value is in lb; lanes>=32: in la
  const float l_tot =
      l_acc + __builtin_bit_cast(float, hi ? la : lb);
  const float rl = 1.0f / l_tot;

  // ---- epilogue: O^T regs are 4-d-contiguous -> b64 Y stores ----
  const int b = bh / 12;
  const int head = bh - b * 12;
  const int row = qt * 128 + wv * 32 + l31;
  unsigned short* yb = Y + ((size_t)(b * 2048 + row)) * 768 + head * 64;
#pragma unroll
  for (int dt = 0; dt < 2; ++dt) {
    const f32x16& oo = dt ? o1 : o0;
#pragma unroll
    for (int g4 = 0; g4 < 4; ++g4) {
      const int d = dt * 32 + g4 * 8 + hi * 4;
      const float a0 = oo[g4 * 4 + 0] * rl;
      const float a1 = oo[g4 * 4 + 1] * rl;
      const float a2 = oo[g4 * 4 + 2] * rl;
      const float a3 = oo[g4 * 4 + 3] * rl;
      const unsigned long long pk =
          (unsigned long long)pk2(a0, a1) | ((unsigned long long)pk2(a2, a3) << 32);
      *(unsigned long long*)(yb + d) = pk;
    }
  }
}

// ---------------------------------------------------------------------------
extern "C" void kernel_launch(void* const* d_in, const int* in_sizes, int n_in,
                              void* d_out, int out_size, void* d_ws, size_t ws_size,
                              hipStream_t stream) {
  const float* x      = (const float*)d_in[0];
  const float* w_attn = (const float*)d_in[1];
  const float* b_attn = (const float*)d_in[2];
  const float* w_proj = (const float*)d_in[3];
  const float* b_proj = (const float*)d_in[4];
  const float* ln_g[2] = {(const float*)d_in[5], (const float*)d_in[7]};
  const float* ln_b[2] = {(const float*)d_in[6], (const float*)d_in[8]};
  float* out = (float*)d_out;

  unsigned short* wAt = (unsigned short*)d_ws;     // (2304,768) bf16
  unsigned short* wPt = wAt + 2304 * 768;          // (768,768)  bf16
  unsigned short* h   = wPt + 768 * 768;           // (8192,768) bf16
  unsigned short* q   = h + 8192 * 768;            // (48,2048,64)
  unsigned short* k   = q + 48 * 2048 * 64;
  unsigned short* vt  = k + 48 * 2048 * 64;        // (48,64,2048) = V^T
  unsigned short* y   = vt + 48 * 2048 * 64;       // (8192,768) bf16

  wt_kernel<<<dim3(72, 24), dim3(32, 8), 0, stream>>>(w_attn, wAt, 2304);
  wt_kernel<<<dim3(24, 24), dim3(32, 8), 0, stream>>>(w_proj, wPt, 768);

  for (int pass = 0; pass < 2; ++pass) {
    const float* xin = pass ? (const float*)out : x;
    ln_kernel<<<8192, 256, 0, stream>>>(xin, ln_g[pass], ln_b[pass], h);
    gemm_kernel<<<dim3(18, 64), 256, 0, stream>>>(h, wAt, b_attn, q, k, vt);
    attn_kernel<<<dim3(48, 16), 256, 0, stream>>>(q, k, vt, y);
    gemm1_kernel<<<dim3(12, 64), 256, 0, stream>>>(y, wPt, b_proj, xin, out);
  }
}

// Round 7
// 374.575 us; speedup vs baseline: 1.2265x; 1.0301x over previous
//
#include <hip/hip_runtime.h>

// ---------------------------------------------------------------------------
// Block = x + attn(ln1(x)); x = x + attn(ln2(x))   (attn twice, no MLP,
// no causal mask, softmax scale = C^-0.5).  B=4 T=2048 C=768 H=12 hd=64.
// R17 = R16 (385.8us) with ONE change: gemm_kernel (qkv GEMM)
// __launch_bounds__(256,2) -> (256,3).  gemm0 is single-buffered (vmcnt(0)
// drain every K-iter); at 2 blocks/CU (8 waves) the drain is exposed; the
// m97 reference runs 3 blocks/CU (12 waves) where cross-block MFMA covers
// it (m114).  VGPR est ~130 < 170 cap @ 3 waves/EU -> no spill expected.
// attn unchanged (71.4us, verified); gemm1/ln/wt unchanged.
// ---------------------------------------------------------------------------

using bf16x8 = __attribute__((ext_vector_type(8))) short;   // 8 bf16 = 4 VGPRs
using f32x4  = __attribute__((ext_vector_type(4))) float;
using f32x16 = __attribute__((ext_vector_type(16))) float;

__device__ __forceinline__ unsigned short f2b(float f) {
  unsigned u = __builtin_bit_cast(unsigned, f);
  u += 0x7FFFu + ((u >> 16) & 1u);          // RNE
  return (unsigned short)(u >> 16);
}
// pack two floats -> two bf16 (RNE) in one dword: lo=a, hi=b
__device__ __forceinline__ unsigned pk2(float a, float b) {
  unsigned ua = __builtin_bit_cast(unsigned, a);
  ua += 0x7FFFu + ((ua >> 16) & 1u);
  unsigned ub = __builtin_bit_cast(unsigned, b);
  ub += 0x7FFFu + ((ub >> 16) & 1u);
  return (ua >> 16) | (ub & 0xFFFF0000u);
}

__device__ __forceinline__ bf16x8 mk8(unsigned a, unsigned b, unsigned c,
                                      unsigned d) {
  union { unsigned u[4]; bf16x8 v; } x;
  x.u[0] = a; x.u[1] = b; x.u[2] = c; x.u[3] = d;
  return x.v;
}

#define ASYNC16(g, l)                                                        \
  __builtin_amdgcn_global_load_lds(                                          \
      (const __attribute__((address_space(1))) void*)(g),                    \
      (__attribute__((address_space(3))) void*)(l), 16, 0, 0)

// swap a.hi32lanes <-> b.lo32lanes (V_PERMLANE32_SWAP_B32)
#define PLSWAP(a, b) asm("v_permlane32_swap_b32 %0, %1" : "+v"(a), "+v"(b))

// ---------------------------------------------------------------------------
// Weight transpose+cast: w (768, N) fp32  ->  wt (N, 768) bf16
// ---------------------------------------------------------------------------
__global__ __launch_bounds__(256) void wt_kernel(const float* __restrict__ w,
                                                 unsigned short* __restrict__ wt,
                                                 int N) {
  __shared__ float tile[32][33];
  const int n0 = blockIdx.x * 32, k0 = blockIdx.y * 32;
  const int tx = threadIdx.x, ty = threadIdx.y;  // (32, 8)
#pragma unroll
  for (int i = 0; i < 32; i += 8)
    tile[ty + i][tx] = w[(size_t)(k0 + ty + i) * N + n0 + tx];
  __syncthreads();
#pragma unroll
  for (int i = 0; i < 32; i += 8)
    wt[(size_t)(n0 + ty + i) * 768 + k0 + tx] = f2b(tile[tx][ty + i]);
}

// ---------------------------------------------------------------------------
// LayerNorm: x (8192, 768) fp32 -> h bf16.  One block per row.
// ---------------------------------------------------------------------------
__global__ __launch_bounds__(256) void ln_kernel(const float* __restrict__ x,
                                                 const float* __restrict__ g,
                                                 const float* __restrict__ b,
                                                 unsigned short* __restrict__ h) {
  __shared__ float red[8];
  const int row = blockIdx.x;
  const int tid = threadIdx.x;
  const float* xr = x + (size_t)row * 768;
  float v0 = xr[tid], v1 = xr[tid + 256], v2 = xr[tid + 512];
  float s = v0 + v1 + v2;
  float s2 = v0 * v0 + v1 * v1 + v2 * v2;
#pragma unroll
  for (int off = 1; off < 64; off <<= 1) {
    s += __shfl_xor(s, off);
    s2 += __shfl_xor(s2, off);
  }
  if ((tid & 63) == 0) { red[tid >> 6] = s; red[4 + (tid >> 6)] = s2; }
  __syncthreads();
  const float S  = red[0] + red[1] + red[2] + red[3];
  const float S2 = red[4] + red[5] + red[6] + red[7];
  const float mu  = S * (1.0f / 768.0f);
  const float var = S2 * (1.0f / 768.0f) - mu * mu;
  const float inv = rsqrtf(var + 1e-5f);
  unsigned short* hr = h + (size_t)row * 768;
  hr[tid]       = f2b((v0 - mu) * inv * g[tid] + b[tid]);
  hr[tid + 256] = f2b((v1 - mu) * inv * g[tid + 256] + b[tid + 256]);
  hr[tid + 512] = f2b((v2 - mu) * inv * g[tid + 512] + b[tid + 512]);
}

// ---------------------------------------------------------------------------
// bf16 GEMM (qkv), m97 pattern: A (M,768) bf16 row-major, Bt (N,768) bf16,
// 128x128 tile, BK=32, 4 waves x 4x4 mfma tiles.  3 blocks/CU (R17).
// EPI: scatter qkv (+bias): q (scaled by c2), k -> (bh,t,d) b16 stores;
//      v -> V^T (bh,d,t) with PACKED b64 stores (r values are t-contig).
// ---------------------------------------------------------------------------
__global__ __launch_bounds__(256, 3) void gemm_kernel(
    const unsigned short* __restrict__ A, const unsigned short* __restrict__ Bt,
    const float* __restrict__ bias,
    unsigned short* __restrict__ q, unsigned short* __restrict__ k,
    unsigned short* __restrict__ vt) {
  __shared__ alignas(16) unsigned short As[128 * 32];
  __shared__ alignas(16) unsigned short Bs[128 * 32];

  const int tid = threadIdx.x;
  const int wv = tid >> 6;
  const int lane = tid & 63;
  const int quad = lane >> 4;
  const int l15 = lane & 15;
  const int m0 = blockIdx.y * 128;
  const int n0 = blockIdx.x * 128;

  const int o0 = wv * 1024 + lane * 16;
  const int rT0 = o0 >> 6, c0 = (o0 & 63) >> 1;
  const int o1 = o0 + 4096;
  const int rT1 = o1 >> 6, c1 = (o1 & 63) >> 1;

  const unsigned short* gA0 = A + (size_t)(m0 + rT0) * 768 + c0;
  const unsigned short* gA1 = A + (size_t)(m0 + rT1) * 768 + c1;
  const unsigned short* gB0 = Bt + (size_t)(n0 + rT0) * 768 + c0;
  const unsigned short* gB1 = Bt + (size_t)(n0 + rT1) * 768 + c1;
  unsigned short* lA0 = &As[wv * 512];
  unsigned short* lA1 = &As[wv * 512 + 2048];
  unsigned short* lB0 = &Bs[wv * 512];
  unsigned short* lB1 = &Bs[wv * 512 + 2048];

  f32x4 acc[4][4];
#pragma unroll
  for (int i = 0; i < 4; ++i)
#pragma unroll
    for (int j = 0; j < 4; ++j) acc[i][j] = {0.f, 0.f, 0.f, 0.f};

  const int mBase = (wv >> 1) * 64;
  const int nBase = (wv & 1) * 64;

  for (int kk = 0; kk < 24; ++kk) {
    const int ko = kk * 32;
    ASYNC16(gA0 + ko, lA0);
    ASYNC16(gA1 + ko, lA1);
    ASYNC16(gB0 + ko, lB0);
    ASYNC16(gB1 + ko, lB1);
    __syncthreads();
    bf16x8 af[4], bfv[4];
#pragma unroll
    for (int mt = 0; mt < 4; ++mt)
      af[mt] = *(const bf16x8*)&As[(mBase + mt * 16 + l15) * 32 + quad * 8];
#pragma unroll
    for (int nt = 0; nt < 4; ++nt)
      bfv[nt] = *(const bf16x8*)&Bs[(nBase + nt * 16 + l15) * 32 + quad * 8];
#pragma unroll
    for (int mt = 0; mt < 4; ++mt)
#pragma unroll
      for (int nt = 0; nt < 4; ++nt)
        acc[mt][nt] = __builtin_amdgcn_mfma_f32_16x16x32_bf16(af[mt], bfv[nt],
                                                              acc[mt][nt], 0, 0, 0);
    __syncthreads();
  }

  const float c2 = 0.052062786090587f;  // 768^-0.5 * log2(e), folded into Q
#pragma unroll
  for (int mt = 0; mt < 4; ++mt) {
#pragma unroll
    for (int nt = 0; nt < 4; ++nt) {
      const int n = n0 + nBase + nt * 16 + l15;
      const int head = n / 192;
      const int rem = n - head * 192;
      const int sel = rem >> 6;
      const int d = rem & 63;
      const float bv = bias[n];
      const int mr = m0 + mBase + mt * 16 + quad * 4;   // r=0 row
      const int bb = mr >> 11;
      const int t = mr & 2047;
      if (sel == 2) {
        // V^T (bh,d,t): 4 r-values are t-contiguous -> one b64 store
        const unsigned long long pk =
            (unsigned long long)pk2(acc[mt][nt][0] + bv, acc[mt][nt][1] + bv) |
            ((unsigned long long)pk2(acc[mt][nt][2] + bv, acc[mt][nt][3] + bv) << 32);
        *(unsigned long long*)&vt[(((size_t)bb * 12 + head) * 64 + d) * 2048 + t] = pk;
      } else {
        unsigned short* tgt = (sel == 0) ? q : k;
        const float sc = (sel == 0) ? c2 : 1.0f;
#pragma unroll
        for (int r = 0; r < 4; ++r)
          tgt[(((size_t)bb * 12 + head) * 2048 + t + r) * 64 + d] =
              f2b((acc[mt][nt][r] + bv) * sc);
      }
    }
  }
}

// ---------------------------------------------------------------------------
// Proj GEMM: 128x64 tile, grid 12x64 = 768 blocks = 3/CU.
// out fp32 = resid + bias + acc.
// ---------------------------------------------------------------------------
__global__ __launch_bounds__(256, 3) void gemm1_kernel(
    const unsigned short* __restrict__ A, const unsigned short* __restrict__ Bt,
    const float* __restrict__ bias, const float* __restrict__ resid,
    float* __restrict__ outF) {
  __shared__ alignas(16) unsigned short As[128 * 32];
  __shared__ alignas(16) unsigned short Bs[64 * 32];

  const int tid = threadIdx.x;
  const int wv = tid >> 6;
  const int lane = tid & 63;
  const int quad = lane >> 4;
  const int l15 = lane & 15;
  const int m0 = blockIdx.y * 128;
  const int n0 = blockIdx.x * 64;

  const int o0 = wv * 1024 + lane * 16;
  const int rT0 = o0 >> 6, c0 = (o0 & 63) >> 1;
  const int o1 = o0 + 4096;
  const int rT1 = o1 >> 6, c1 = (o1 & 63) >> 1;

  const unsigned short* gA0 = A + (size_t)(m0 + rT0) * 768 + c0;
  const unsigned short* gA1 = A + (size_t)(m0 + rT1) * 768 + c1;
  const unsigned short* gB0 = Bt + (size_t)(n0 + rT0) * 768 + c0;
  unsigned short* lA0 = &As[wv * 512];
  unsigned short* lA1 = &As[wv * 512 + 2048];
  unsigned short* lB0 = &Bs[wv * 512];

  f32x4 acc[4][2];
#pragma unroll
  for (int i = 0; i < 4; ++i)
#pragma unroll
    for (int j = 0; j < 2; ++j) acc[i][j] = {0.f, 0.f, 0.f, 0.f};

  const int mBase = (wv >> 1) * 64;
  const int nBase = (wv & 1) * 32;

  for (int kk = 0; kk < 24; ++kk) {
    const int ko = kk * 32;
    ASYNC16(gA0 + ko, lA0);
    ASYNC16(gA1 + ko, lA1);
    ASYNC16(gB0 + ko, lB0);
    __syncthreads();
    bf16x8 af[4], bfv[2];
#pragma unroll
    for (int mt = 0; mt < 4; ++mt)
      af[mt] = *(const bf16x8*)&As[(mBase + mt * 16 + l15) * 32 + quad * 8];
#pragma unroll
    for (int nt = 0; nt < 2; ++nt)
      bfv[nt] = *(const bf16x8*)&Bs[(nBase + nt * 16 + l15) * 32 + quad * 8];
#pragma unroll
    for (int mt = 0; mt < 4; ++mt)
#pragma unroll
      for (int nt = 0; nt < 2; ++nt)
        acc[mt][nt] = __builtin_amdgcn_mfma_f32_16x16x32_bf16(af[mt], bfv[nt],
                                                              acc[mt][nt], 0, 0, 0);
    __syncthreads();
  }

#pragma unroll
  for (int mt = 0; mt < 4; ++mt) {
#pragma unroll
    for (int nt = 0; nt < 2; ++nt) {
      const int n = n0 + nBase + nt * 16 + l15;
      const float bv = bias[n];
#pragma unroll
      for (int r = 0; r < 4; ++r) {
        const int m = m0 + mBase + mt * 16 + quad * 4 + r;
        const size_t idx = (size_t)m * 768 + n;
        outF[idx] = resid[idx] + bv + acc[mt][nt][r];
      }
    }
  }
}

// ---------------------------------------------------------------------------
// Flash attention (verified 71.4us): 32x32x16 MFMA, in-register P via
// permlane swaps, K/V via swizzled global_load_lds dbuf, 1 barrier/chunk.
//   S^T = K Q^T (Q pre-scaled by c2) -> P = exp2(S^T) -> bf16 via
//   v_cvt_pk_bf16_f32 -> O^T += V^T P^T ;  l += exact f32 exp sum (VALU).
// Per wave: 32 q rows, chunk = 64 t.  Block: 4 waves = 128 q.
// ---------------------------------------------------------------------------
__global__ __launch_bounds__(256, 3) void attn_kernel(
    const unsigned short* __restrict__ Q, const unsigned short* __restrict__ Km,
    const unsigned short* __restrict__ Vt, unsigned short* __restrict__ Y) {
  __shared__ alignas(16) unsigned short Ks[2][64 * 64];  // [t][d], swizzled
  __shared__ alignas(16) unsigned short Vs[2][64 * 64];  // [d][t], swizzled

  const int bh   = blockIdx.x;
  const int qt   = blockIdx.y;
  const int tid  = threadIdx.x;
  const int wv   = tid >> 6;
  const int lane = tid & 63;
  const int l31  = lane & 31;
  const int hi   = lane >> 5;
  const int s7   = l31 & 7;
  const size_t bhT = (size_t)bh * 2048;

  // ---- Q fragments: B-operand, lane holds Q[q=l31][d=ks*16+hi*8+j] --------
  bf16x8 qf[4];
  {
    const unsigned short* qb =
        Q + (bhT + qt * 128 + wv * 32 + l31) * 64 + hi * 8;
#pragma unroll
    for (int ks = 0; ks < 4; ++ks) qf[ks] = *(const bf16x8*)(qb + ks * 16);
  }

  // ---- staging: linear LDS dest, inverse-swizzled global source -----------
  // LDS slot L (bytes): row r = L>>7, in-row byte = (L&127) ^ ((r&7)<<4)
  const int L0 = wv * 1024 + (lane << 4);
  const int L1 = L0 + 4096;
  const int r0 = L0 >> 7, b0 = (L0 & 127) ^ ((r0 & 7) << 4);
  const int r1 = L1 >> 7, b1 = (L1 & 127) ^ ((r1 & 7) << 4);
  const unsigned short* kg0 = Km + (bhT + r0) * 64 + (b0 >> 1);
  const unsigned short* kg1 = Km + (bhT + r1) * 64 + (b1 >> 1);
  const unsigned short* vg0 = Vt + ((size_t)bh * 64 + r0) * 2048 + (b0 >> 1);
  const unsigned short* vg1 = Vt + ((size_t)bh * 64 + r1) * 2048 + (b1 >> 1);
  const int kb0 = wv * 512, kb1 = wv * 512 + 2048;  // ushort units

  f32x16 o0, o1;
#pragma unroll
  for (int i = 0; i < 16; ++i) { o0[i] = 0.f; o1[i] = 0.f; }
  float l_acc = 0.f;

  // prologue: stage chunk 0 into buf 0
  ASYNC16(kg0, &Ks[0][kb0]);
  ASYNC16(kg1, &Ks[0][kb1]);
  ASYNC16(vg0, &Vs[0][kb0]);
  ASYNC16(vg1, &Vs[0][kb1]);
  __syncthreads();

  for (int c = 0; c < 32; ++c) {
    const int p = c & 1;
    if (c < 31) {  // stage c+1 into the other buffer; lands by chunk-end sync
      const int ka = (c + 1) * 4096, va = (c + 1) * 64;
      ASYNC16(kg0 + ka, &Ks[p ^ 1][kb0]);
      ASYNC16(kg1 + ka, &Ks[p ^ 1][kb1]);
      ASYNC16(vg0 + va, &Vs[p ^ 1][kb0]);
      ASYNC16(vg1 + va, &Vs[p ^ 1][kb1]);
    }
    const unsigned short* Kp = &Ks[p][0];
    const unsigned short* Vp = &Vs[p][0];

#pragma unroll
    for (int tt = 0; tt < 2; ++tt) {
      // ---- S tile (32t x 32q): 4 chained k-steps ----
      f32x16 s;
#pragma unroll
      for (int i = 0; i < 16; ++i) s[i] = 0.f;
#pragma unroll
      for (int ks = 0; ks < 4; ++ks) {
        const int off = tt * 4096 + l31 * 128 + (((ks * 2 + hi) ^ s7) << 4);
        bf16x8 kf = *(const bf16x8*)&Kp[off >> 1];
        s = __builtin_amdgcn_mfma_f32_32x32x16_bf16(kf, qf[ks], s, 0, 0, 0);
      }

      // ---- P = exp2(S) -> bf16 (cvt_pk, RNE); l += exact f32 sum ----
      unsigned dw[8];
      float lc = 0.f;
#pragma unroll
      for (int r2 = 0; r2 < 8; ++r2) {
        const float e0 = __builtin_amdgcn_exp2f(s[2 * r2]);
        const float e1 = __builtin_amdgcn_exp2f(s[2 * r2 + 1]);
        lc += e0 + e1;
        asm("v_cvt_pk_bf16_f32 %0, %1, %2" : "=v"(dw[r2]) : "v"(e0), "v"(e1));
      }
      l_acc += lc;

      // ---- C-layout -> B-frag: one swap yields two pf words ----
      PLSWAP(dw[0], dw[2]);
      PLSWAP(dw[1], dw[3]);
      PLSWAP(dw[4], dw[6]);
      PLSWAP(dw[5], dw[7]);
      const bf16x8 pf0 = mk8(dw[0], dw[1], dw[2], dw[3]);  // t in [tt*32, +16)
      const bf16x8 pf1 = mk8(dw[4], dw[5], dw[6], dw[7]);  // t in [+16, +32)

      // ---- O^T += V^T P^T ----
#pragma unroll
      for (int dt = 0; dt < 2; ++dt) {
        const int vb = dt * 4096 + l31 * 128;
        const int kv0 = tt * 2, kv1 = tt * 2 + 1;
        bf16x8 vf0 = *(const bf16x8*)&Vp[(vb + (((kv0 * 2 + hi) ^ s7) << 4)) >> 1];
        bf16x8 vf1 = *(const bf16x8*)&Vp[(vb + (((kv1 * 2 + hi) ^ s7) << 4)) >> 1];
        if (dt == 0) {
          o0 = __builtin_amdgcn_mfma_f32_32x32x16_bf16(vf0, pf0, o0, 0, 0, 0);
          o0 = __builtin_amdgcn_mfma_f32_32x32x16_bf16(vf1, pf1, o0, 0, 0, 0);
        } else {
          o1 = __builtin_amdgcn_mfma_f32_32x32x16_bf16(vf0, pf0, o1, 0, 0, 0);
          o1 = __builtin_amdgcn_mfma_f32_32x32x16_bf16(vf1, pf1, o1, 0, 0, 0);
        }
      }
    }
    __syncthreads();  // waits vmcnt (next-chunk stages landed) + all waves
  }

  // ---- l: add the other 32-lane half's partial ----
  unsigned la = __builtin_bit_cast(unsigned, l_acc), lb = la;
  PLSWAP(la, lb);
  // lanes<32: other half's value is in lb; lanes>=32: in la
  const float l_tot =
      l_acc + __builtin_bit_cast(float, hi ? la : lb);
  const float rl = 1.0f / l_tot;

  // ---- epilogue: O^T regs are 4-d-contiguous -> b64 Y stores ----
  const int b = bh / 12;
  const int head = bh - b * 12;
  const int row = qt * 128 + wv * 32 + l31;
  unsigned short* yb = Y + ((size_t)(b * 2048 + row)) * 768 + head * 64;
#pragma unroll
  for (int dt = 0; dt < 2; ++dt) {
    const f32x16& oo = dt ? o1 : o0;
#pragma unroll
    for (int g4 = 0; g4 < 4; ++g4) {
      const int d = dt * 32 + g4 * 8 + hi * 4;
      const float a0 = oo[g4 * 4 + 0] * rl;
      const float a1 = oo[g4 * 4 + 1] * rl;
      const float a2 = oo[g4 * 4 + 2] * rl;
      const float a3 = oo[g4 * 4 + 3] * rl;
      const unsigned long long pk =
          (unsigned long long)pk2(a0, a1) | ((unsigned long long)pk2(a2, a3) << 32);
      *(unsigned long long*)(yb + d) = pk;
    }
  }
}

// ---------------------------------------------------------------------------
extern "C" void kernel_launch(void* const* d_in, const int* in_sizes, int n_in,
                              void* d_out, int out_size, void* d_ws, size_t ws_size,
                              hipStream_t stream) {
  const float* x      = (const float*)d_in[0];
  const float* w_attn = (const float*)d_in[1];
  const float* b_attn = (const float*)d_in[2];
  const float* w_proj = (const float*)d_in[3];
  const float* b_proj = (const float*)d_in[4];
  const float* ln_g[2] = {(const float*)d_in[5], (const float*)d_in[7]};
  const float* ln_b[2] = {(const float*)d_in[6], (const float*)d_in[8]};
  float* out = (float*)d_out;

  unsigned short* wAt = (unsigned short*)d_ws;     // (2304,768) bf16
  unsigned short* wPt = wAt + 2304 * 768;          // (768,768)  bf16
  unsigned short* h   = wPt + 768 * 768;           // (8192,768) bf16
  unsigned short* q   = h + 8192 * 768;            // (48,2048,64)
  unsigned short* k   = q + 48 * 2048 * 64;
  unsigned short* vt  = k + 48 * 2048 * 64;        // (48,64,2048) = V^T
  unsigned short* y   = vt + 48 * 2048 * 64;       // (8192,768) bf16

  wt_kernel<<<dim3(72, 24), dim3(32, 8), 0, stream>>>(w_attn, wAt, 2304);
  wt_kernel<<<dim3(24, 24), dim3(32, 8), 0, stream>>>(w_proj, wPt, 768);

  for (int pass = 0; pass < 2; ++pass) {
    const float* xin = pass ? (const float*)out : x;
    ln_kernel<<<8192, 256, 0, stream>>>(xin, ln_g[pass], ln_b[pass], h);
    gemm_kernel<<<dim3(18, 64), 256, 0, stream>>>(h, wAt, b_attn, q, k, vt);
    attn_kernel<<<dim3(48, 16), 256, 0, stream>>>(q, k, vt, y);
    gemm1_kernel<<<dim3(12, 64), 256, 0, stream>>>(y, wPt, b_proj, xin, out);
  }
}